// Round 4
// baseline (694.171 us; speedup 1.0000x reference)
//
#include <hip/hip_runtime.h>
#include <hip/hip_bf16.h>

#define N_NODES 10000
#define DIM 512
#define NCLS 64
#define BM 64
#define BN 128
#define BK 64
#define ELLW 64

typedef __hip_bfloat16 bf16;
typedef unsigned short u16;
typedef unsigned int u32;
typedef __attribute__((ext_vector_type(8))) short short8;
typedef __attribute__((ext_vector_type(4))) float f32x4;

__device__ __forceinline__ float b2f(bf16 v) { return __bfloat162float(v); }
__device__ __forceinline__ float ldIn(const void* p, size_t i, int isb) {
    return isb ? b2f(((const bf16*)p)[i]) : ((const float*)p)[i];
}
__device__ __forceinline__ int getE(const int* ei, int is64, int flat) {
    return is64 ? ei[2 * (size_t)flat] : ei[flat];
}
__device__ __forceinline__ void load_lds16(const bf16* g, bf16* l) {
    __builtin_amdgcn_global_load_lds(
        (const __attribute__((address_space(1))) void*)g,
        (__attribute__((address_space(3))) void*)l, 16, 0, 0);
}
__device__ __forceinline__ float blo(u32 v) { union {u32 u; float f;} x; x.u = v << 16; return x.f; }
__device__ __forceinline__ float bhi(u32 v) { union {u32 u; float f;} x; x.u = v & 0xffff0000u; return x.f; }
__device__ __forceinline__ u16  f2b(float f) { bf16 h = __float2bfloat16(f); return *(u16*)&h; }

// ---- fused preamble. MEASUREMENT ROUND: idempotent block types repeat `reps`
//      times (opaque runtime count + memory clobber -> real re-execution);
//      ELL build runs exactly once so cursor/ell stay correct. ----
__global__ __launch_bounds__(256) void convert_all(
        const void* __restrict__ X, const void* __restrict__ W1,
        const void* __restrict__ W2, const void* __restrict__ Wc,
        const void* __restrict__ b1, const void* __restrict__ b2,
        const void* __restrict__ bc, const int* __restrict__ ei,
        int* __restrict__ cursor, int* __restrict__ ell,
        bf16* __restrict__ Xb, bf16* __restrict__ Wt1, bf16* __restrict__ Wt2,
        bf16* __restrict__ Wtc, float* __restrict__ bF1, float* __restrict__ bF2,
        float* __restrict__ bFc, int E, int reps) {
    __shared__ float tile[32][33];
    __shared__ int sflags[2];
    int b = blockIdx.x, t = threadIdx.x;

    if (t < 64) {
        const u16* x16 = (const u16*)X;
        int cf = 0;
        #pragma unroll
        for (int j = 0; j < 4; j++) {
            int e = (x16[t * 4 + j] >> 7) & 0xFF;
            cf += (e >= 97 && e <= 157) ? 1 : 0;
        }
        #pragma unroll
        for (int o = 32; o > 0; o >>= 1) cf += __shfl_xor(cf, o, 64);
        int cz = (t < 32) ? ((ei[2 * t + 1] == 0) ? 1 : 0) : 0;
        #pragma unroll
        for (int o = 32; o > 0; o >>= 1) cz += __shfl_xor(cz, o, 64);
        if (t == 0) { sflags[0] = (cf >= 200) ? 1 : 0; sflags[1] = (cz >= 16) ? 1 : 0; }
    }
    __syncthreads();
    int isb = sflags[0], is64 = sflags[1];

    if (b < 2500) {                      // x: 8 elems/thread
        for (int rp = 0; rp < reps; rp++) {
            int base = (b * 256 + t) * 8;
            bf16 o[8];
            if (isb) {
                *(uint4*)o = *(const uint4*)((const bf16*)X + base);
            } else {
                const float* Xf = (const float*)X + base;
                float4 v0 = *(const float4*)Xf, v1 = *(const float4*)(Xf + 4);
                o[0] = __float2bfloat16(v0.x); o[1] = __float2bfloat16(v0.y);
                o[2] = __float2bfloat16(v0.z); o[3] = __float2bfloat16(v0.w);
                o[4] = __float2bfloat16(v1.x); o[5] = __float2bfloat16(v1.y);
                o[6] = __float2bfloat16(v1.z); o[7] = __float2bfloat16(v1.w);
            }
            *(uint4*)&Xb[base] = *(uint4*)o;
            asm volatile("" ::: "memory");
        }
    } else if (b < 3044) {               // W[K][N] -> Wt[N][K] (32x32 tiles)
        for (int rp = 0; rp < reps; rp++) {
            const void* W; bf16* Wt; int N; int bb = b - 2500;
            if (bb < 256)      { W = W1; Wt = Wt1; N = DIM; }
            else if (bb < 512) { W = W2; Wt = Wt2; N = DIM;  bb -= 256; }
            else               { W = Wc; Wt = Wtc; N = NCLS; bb -= 512; }
            int nt = N / 32;
            int n0 = (bb % nt) * 32, k0 = (bb / nt) * 32;
            int tx = t & 31, ty = t >> 5;
            for (int r = ty; r < 32; r += 8)
                tile[r][tx] = ldIn(W, (size_t)(k0 + r) * N + n0 + tx, isb);
            __syncthreads();
            for (int r = ty; r < 32; r += 8)
                Wt[(size_t)(n0 + r) * DIM + k0 + tx] = __float2bfloat16(tile[tx][r]);
            __syncthreads();
            asm volatile("" ::: "memory");
        }
    } else if (b == 3044) {              // biases -> f32
        for (int rp = 0; rp < reps; rp++) {
            for (int i = t; i < 2 * DIM + NCLS; i += 256) {
                if (i < DIM)            bF1[i] = ldIn(b1, i, isb);
                else if (i < 2 * DIM)   bF2[i - DIM] = ldIn(b2, i - DIM, isb);
                else                    bFc[i - 2 * DIM] = ldIn(bc, i - 2 * DIM, isb);
            }
            asm volatile("" ::: "memory");
        }
    } else {                             // ELL build: ONCE (not idempotent)
        int e = (b - 3045) * 256 + t;
        if (e >= E) return;
        int s = getE(ei, is64, e), d = getE(ei, is64, E + e);
        if (s == d || (unsigned)s >= N_NODES || (unsigned)d >= N_NODES) return;
        int pos = atomicAdd(&cursor[d], 1);
        ell[d * ELLW + (pos & (ELLW - 1))] = s;
    }
}

// ---- MFMA GEMM (r3 logic verbatim), body repeated `reps` times ----
__global__ __launch_bounds__(256) void gemm_mfma(
        const bf16* __restrict__ A, const bf16* __restrict__ Bt,
        bf16* __restrict__ C, int M, int Nc, int K,
        const int* __restrict__ deg, int reps) {
    __shared__ bf16 At[2][BM * BK];
    __shared__ bf16 Bts[2][BN * BK];
    int t = threadIdx.x;
    int w = t >> 6, l = t & 63;

    int bid = blockIdx.x;
    int xcd = bid & 7, i0 = bid >> 3;
    int tile = (xcd < 4 ? xcd * 79 : 316 + (xcd - 4) * 78) + i0;
    int bm = (tile >> 2) * BM, bn = (tile & 3) * BN;
    int wn = w * 32;

    int srow8 = l >> 3;
    int sk8b  = (((l & 7) ^ srow8) * 8);

    for (int rp = 0; rp < reps; rp++) {
        f32x4 acc[4][2] = {};

        #pragma unroll
        for (int i = 0; i < 2; i++) {
            int c = w * 2 + i;
            load_lds16(A + (size_t)(bm + c * 8 + srow8) * K + sk8b, &At[0][c * 512]);
        }
        #pragma unroll
        for (int i = 0; i < 4; i++) {
            int c = w * 4 + i;
            load_lds16(Bt + (size_t)(bn + c * 8 + srow8) * K + sk8b, &Bts[0][c * 512]);
        }
        __syncthreads();

        for (int k0 = 0; k0 < K; k0 += BK) {
            int cur = (k0 >> 6) & 1;
            if (k0 + BK < K) {
                #pragma unroll
                for (int i = 0; i < 2; i++) {
                    int c = w * 2 + i;
                    load_lds16(A + (size_t)(bm + c * 8 + srow8) * K + k0 + BK + sk8b,
                               &At[cur ^ 1][c * 512]);
                }
                #pragma unroll
                for (int i = 0; i < 4; i++) {
                    int c = w * 4 + i;
                    load_lds16(Bt + (size_t)(bn + c * 8 + srow8) * K + k0 + BK + sk8b,
                               &Bts[cur ^ 1][c * 512]);
                }
            }
            #pragma unroll
            for (int kk = 0; kk < BK; kk += 32) {
                short8 af[4], bfr[2];
                int slot = (((kk >> 3) + (l >> 4)) ^ (l & 7)) * 8;
                #pragma unroll
                for (int i = 0; i < 4; i++)
                    af[i] = *(const short8*)&At[cur][(i * 16 + (l & 15)) * BK + slot];
                #pragma unroll
                for (int j = 0; j < 2; j++)
                    bfr[j] = *(const short8*)&Bts[cur][(wn + j * 16 + (l & 15)) * BK + slot];
                #pragma unroll
                for (int i = 0; i < 4; i++)
                    #pragma unroll
                    for (int j = 0; j < 2; j++)
                        acc[i][j] = __builtin_amdgcn_mfma_f32_16x16x32_bf16(
                                        af[i], bfr[j], acc[i][j], 0, 0, 0);
            }
            __syncthreads();
        }

        int col = l & 15, rq = (l >> 4) * 4;
        #pragma unroll
        for (int i = 0; i < 4; i++) {
            #pragma unroll
            for (int r = 0; r < 4; r++) {
                int gm = bm + i * 16 + rq + r;
                if (gm >= M) continue;
                float rs = rsqrtf((float)deg[gm] + 1.0f);
                #pragma unroll
                for (int j = 0; j < 2; j++) {
                    int gn = bn + wn + j * 16 + col;
                    C[(size_t)gm * Nc + gn] = __float2bfloat16(acc[i][j][r] * rs);
                }
            }
        }
        __syncthreads();
        asm volatile("" ::: "memory");
    }
}

// ---- gather (r3 logic verbatim), body repeated `reps` times (x16 this round:
//      reps 2..16 should be L2-hot if the XCD-chunking theory holds ->
//      FETCH_SIZE ~ first-touch only, hbm_gbps LOW). ----
__global__ __launch_bounds__(256) void gather_ell(
        const int* __restrict__ cursor, const int* __restrict__ ell,
        const bf16* __restrict__ Hs, const float* __restrict__ bias,
        bf16* __restrict__ Out, int relu, int reps) {
    int t = threadIdx.x;
    int w = t >> 6, lane = t & 63;
    int chunk = blockIdx.x & 3;
    int wid = (blockIdx.x >> 2) * 4 + w;
    if (wid >= N_NODES) return;
    int c0 = chunk * 128 + lane * 2;

    for (int rp = 0; rp < reps; rp++) {
        int cnt0 = cursor[wid];
        int cnt = min(cnt0, ELLW);
        int idx = ell[wid * ELLW + lane];

        u32 v = *(const u32*)(Hs + (size_t)wid * DIM + c0);
        float a0 = blo(v), a1 = bhi(v);

        int e = 0;
        for (; e + 7 < cnt; e += 8) {
            u32 r[8];
            #pragma unroll
            for (int b = 0; b < 8; b++) {
                int s = __shfl(idx, e + b, 64);
                r[b] = *(const u32*)(Hs + (size_t)s * DIM + c0);
            }
            a0 += ((blo(r[0]) + blo(r[1])) + (blo(r[2]) + blo(r[3])))
                + ((blo(r[4]) + blo(r[5])) + (blo(r[6]) + blo(r[7])));
            a1 += ((bhi(r[0]) + bhi(r[1])) + (bhi(r[2]) + bhi(r[3])))
                + ((bhi(r[4]) + bhi(r[5])) + (bhi(r[6]) + bhi(r[7])));
        }
        for (; e < cnt; e++) {
            int s = __shfl(idx, e, 64);
            u32 rv = *(const u32*)(Hs + (size_t)s * DIM + c0);
            a0 += blo(rv); a1 += bhi(rv);
        }

        float ds = rsqrtf((float)cnt0 + 1.0f);
        float v0 = a0 * ds + bias[c0];
        float v1 = a1 * ds + bias[c0 + 1];
        if (relu) { v0 = fmaxf(v0, 0.0f); v1 = fmaxf(v1, 0.0f); }
        u32 o = (u32)f2b(v0) | ((u32)f2b(v1) << 16);
        *(u32*)(Out + (size_t)wid * DIM + c0) = o;
        asm volatile("" ::: "memory");
    }
}

// ---- fused classifier + log-softmax (r3 logic verbatim), repeated `reps` ----
__global__ __launch_bounds__(64) void cls_lsm_kernel(
        const bf16* __restrict__ A, const bf16* __restrict__ Wct,
        const float* __restrict__ bias, float* __restrict__ out, int M, int reps) {
    int l = threadIdx.x;
    int row0 = blockIdx.x * 16;
    int q = l >> 4, col15 = l & 15;

    for (int rp = 0; rp < reps; rp++) {
        f32x4 acc[4] = {};
        #pragma unroll 4
        for (int k0 = 0; k0 < DIM; k0 += 32) {
            short8 af = *(const short8*)&A[(size_t)(row0 + col15) * DIM + k0 + q * 8];
            #pragma unroll
            for (int j = 0; j < 4; j++) {
                short8 bfr = *(const short8*)&Wct[(size_t)(j * 16 + col15) * DIM + k0 + q * 8];
                acc[j] = __builtin_amdgcn_mfma_f32_16x16x32_bf16(af, bfr, acc[j], 0, 0, 0);
            }
        }

        float bcol[4];
        #pragma unroll
        for (int j = 0; j < 4; j++) bcol[j] = bias[j * 16 + col15];

        #pragma unroll
        for (int r = 0; r < 4; r++) {
            int row = row0 + q * 4 + r;
            float v[4];
            #pragma unroll
            for (int j = 0; j < 4; j++) v[j] = acc[j][r] + bcol[j];
            float m = fmaxf(fmaxf(v[0], v[1]), fmaxf(v[2], v[3]));
            #pragma unroll
            for (int o = 8; o > 0; o >>= 1) m = fmaxf(m, __shfl_xor(m, o, 64));
            float s = __expf(v[0] - m) + __expf(v[1] - m) + __expf(v[2] - m) + __expf(v[3] - m);
            #pragma unroll
            for (int o = 8; o > 0; o >>= 1) s += __shfl_xor(s, o, 64);
            float lse = m + __logf(s);
            if (row < M) {
                #pragma unroll
                for (int j = 0; j < 4; j++) {
                    out[(size_t)row * NCLS + j * 16 + col15] = v[j];
                    out[(size_t)M * NCLS + (size_t)row * NCLS + j * 16 + col15] = v[j] - lse;
                }
            }
        }
        asm volatile("" ::: "memory");
    }
}

extern "C" void kernel_launch(void* const* d_in, const int* in_sizes, int n_in,
                              void* d_out, int out_size, void* d_ws, size_t ws_size,
                              hipStream_t stream) {
    const void* x  = d_in[0];
    const int*  ei = (const int*)d_in[1];
    const void* W1 = d_in[2];
    const void* b1 = d_in[3];
    const void* W2 = d_in[4];
    const void* b2 = d_in[5];
    const void* Wc = d_in[6];
    const void* bc = d_in[7];
    float* out = (float*)d_out;
    int E = in_sizes[1] / 2;

    char* ws = (char*)d_ws;
    float* bF1    = (float*)ws;
    float* bF2    = (float*)(ws + 4096);
    float* bFc    = (float*)(ws + 8192);
    int*   cursor = (int*)(ws + 65536);
    int*   ell    = (int*)(ws + 131072);
    bf16*  xb     = (bf16*) (ws + 4194304);
    bf16*  Wt1    = (bf16*) (ws + 14680064);
    bf16*  Wt2    = (bf16*) (ws + 15204352);
    bf16*  Wct    = (bf16*) (ws + 15728640);
    bf16*  B0     = (bf16*) (ws + 16777216);
    bf16*  B1     = (bf16*) (ws + 27262976);

    int gConv = 3045 + (E + 255) / 256;
    const int GEMM_GRID = 628;

    // MEASUREMENT ROUND multipliers (r3 logic unchanged; reps=1 restores r3)
    const int R_CONV = 8, R_GEMM = 8, R_GATH = 16, R_CLS = 8;

    hipMemsetAsync(cursor, 0, N_NODES * sizeof(int), stream);
    convert_all<<<gConv, 256, 0, stream>>>(x, W1, W2, Wc, b1, b2, bc, ei,
                                           cursor, ell, xb, Wt1, Wt2, Wct,
                                           bF1, bF2, bFc, E, R_CONV);

    gemm_mfma<<<GEMM_GRID, 256, 0, stream>>>(xb, Wt1, B0, N_NODES, DIM, DIM, cursor, R_GEMM);
    gather_ell<<<N_NODES, 256, 0, stream>>>(cursor, ell, B0, bF1, B1, 1, R_GATH);

    gemm_mfma<<<GEMM_GRID, 256, 0, stream>>>(B1, Wt2, B0, N_NODES, DIM, DIM, cursor, R_GEMM);
    gather_ell<<<N_NODES, 256, 0, stream>>>(cursor, ell, B0, bF2, B1, 0, R_GATH);

    cls_lsm_kernel<<<(N_NODES + 15) / 16, 64, 0, stream>>>(B1, Wct, bFc, out, N_NODES, R_CLS);
}

// Round 5
// 172.531 us; speedup vs baseline: 4.0235x; 4.0235x over previous
//
#include <hip/hip_runtime.h>
#include <hip/hip_bf16.h>

#define N_NODES 10000
#define DIM 512
#define NCLS 64
#define BM 64
#define BN 128
#define BK 64
#define ELLW 64

typedef __hip_bfloat16 bf16;
typedef unsigned short u16;
typedef unsigned int u32;
typedef __attribute__((ext_vector_type(8))) short short8;
typedef __attribute__((ext_vector_type(4))) float f32x4;

__device__ __forceinline__ float b2f(bf16 v) { return __bfloat162float(v); }
__device__ __forceinline__ float ldIn(const void* p, size_t i, int isb) {
    return isb ? b2f(((const bf16*)p)[i]) : ((const float*)p)[i];
}
__device__ __forceinline__ int getE(const int* ei, int is64, int flat) {
    return is64 ? ei[2 * (size_t)flat] : ei[flat];
}
__device__ __forceinline__ void load_lds16(const bf16* g, bf16* l) {
    __builtin_amdgcn_global_load_lds(
        (const __attribute__((address_space(1))) void*)g,
        (__attribute__((address_space(3))) void*)l, 16, 0, 0);
}
__device__ __forceinline__ float blo(u32 v) { union {u32 u; float f;} x; x.u = v << 16; return x.f; }
__device__ __forceinline__ float bhi(u32 v) { union {u32 u; float f;} x; x.u = v & 0xffff0000u; return x.f; }
__device__ __forceinline__ u16  f2b(float f) { bf16 h = __float2bfloat16(f); return *(u16*)&h; }

// ---- fused preamble: dtype sniff per block | x->bf16 | 3 weight transposes |
//      bias->f32 | ELL build. cursor pre-zeroed by hipMemsetAsync. ----
__global__ __launch_bounds__(256) void convert_all(
        const void* __restrict__ X, const void* __restrict__ W1,
        const void* __restrict__ W2, const void* __restrict__ Wc,
        const void* __restrict__ b1, const void* __restrict__ b2,
        const void* __restrict__ bc, const int* __restrict__ ei,
        int* __restrict__ cursor, int* __restrict__ ell,
        bf16* __restrict__ Xb, bf16* __restrict__ Wt1, bf16* __restrict__ Wt2,
        bf16* __restrict__ Wtc, float* __restrict__ bF1, float* __restrict__ bF2,
        float* __restrict__ bFc, int E) {
    __shared__ float tile[32][33];
    __shared__ int sflags[2];
    int b = blockIdx.x, t = threadIdx.x;

    // per-block dtype sniff (X first 256 u16 + edge col check; L2-hot)
    if (t < 64) {
        const u16* x16 = (const u16*)X;
        int cf = 0;
        #pragma unroll
        for (int j = 0; j < 4; j++) {
            int e = (x16[t * 4 + j] >> 7) & 0xFF;
            cf += (e >= 97 && e <= 157) ? 1 : 0;
        }
        #pragma unroll
        for (int o = 32; o > 0; o >>= 1) cf += __shfl_xor(cf, o, 64);
        int cz = (t < 32) ? ((ei[2 * t + 1] == 0) ? 1 : 0) : 0;
        #pragma unroll
        for (int o = 32; o > 0; o >>= 1) cz += __shfl_xor(cz, o, 64);
        if (t == 0) { sflags[0] = (cf >= 200) ? 1 : 0; sflags[1] = (cz >= 16) ? 1 : 0; }
    }
    __syncthreads();
    int isb = sflags[0], is64 = sflags[1];

    if (b < 2500) {                      // x: 8 elems/thread, 5.12M total
        int base = (b * 256 + t) * 8;
        bf16 o[8];
        if (isb) {
            *(uint4*)o = *(const uint4*)((const bf16*)X + base);
        } else {
            const float* Xf = (const float*)X + base;
            float4 v0 = *(const float4*)Xf, v1 = *(const float4*)(Xf + 4);
            o[0] = __float2bfloat16(v0.x); o[1] = __float2bfloat16(v0.y);
            o[2] = __float2bfloat16(v0.z); o[3] = __float2bfloat16(v0.w);
            o[4] = __float2bfloat16(v1.x); o[5] = __float2bfloat16(v1.y);
            o[6] = __float2bfloat16(v1.z); o[7] = __float2bfloat16(v1.w);
        }
        *(uint4*)&Xb[base] = *(uint4*)o;
    } else if (b < 3044) {               // W[K][N] -> Wt[N][K] (32x32 tiles)
        const void* W; bf16* Wt; int N; int bb = b - 2500;
        if (bb < 256)      { W = W1; Wt = Wt1; N = DIM; }
        else if (bb < 512) { W = W2; Wt = Wt2; N = DIM;  bb -= 256; }
        else               { W = Wc; Wt = Wtc; N = NCLS; bb -= 512; }
        int nt = N / 32;
        int n0 = (bb % nt) * 32, k0 = (bb / nt) * 32;
        int tx = t & 31, ty = t >> 5;
        for (int r = ty; r < 32; r += 8)
            tile[r][tx] = ldIn(W, (size_t)(k0 + r) * N + n0 + tx, isb);
        __syncthreads();
        for (int r = ty; r < 32; r += 8)
            Wt[(size_t)(n0 + r) * DIM + k0 + tx] = __float2bfloat16(tile[tx][r]);
    } else if (b == 3044) {              // biases -> f32 (1088 elems)
        for (int i = t; i < 2 * DIM + NCLS; i += 256) {
            if (i < DIM)            bF1[i] = ldIn(b1, i, isb);
            else if (i < 2 * DIM)   bF2[i - DIM] = ldIn(b2, i - DIM, isb);
            else                    bFc[i - 2 * DIM] = ldIn(bc, i - 2 * DIM, isb);
        }
    } else {                             // ELL build: one atomic per edge
        int e = (b - 3045) * 256 + t;
        if (e >= E) return;
        int s = getE(ei, is64, e), d = getE(ei, is64, E + e);
        if (s == d || (unsigned)s >= N_NODES || (unsigned)d >= N_NODES) return;
        int pos = atomicAdd(&cursor[d], 1);
        ell[d * ELLW + (pos & (ELLW - 1))] = s;
    }
}

// ---- MFMA GEMM (r3 verbatim): T2 swizzle + 2-phase dbuf + XCD-affine tiles ----
__global__ __launch_bounds__(256) void gemm_mfma(
        const bf16* __restrict__ A, const bf16* __restrict__ Bt,
        bf16* __restrict__ C, int M, int Nc, int K,
        const int* __restrict__ deg) {
    __shared__ bf16 At[2][BM * BK];     // 2 x 8 KB
    __shared__ bf16 Bts[2][BN * BK];    // 2 x 16 KB
    int t = threadIdx.x;
    int w = t >> 6, l = t & 63;

    int bid = blockIdx.x;
    int xcd = bid & 7, i0 = bid >> 3;
    int tile = (xcd < 4 ? xcd * 79 : 316 + (xcd - 4) * 78) + i0;
    int bm = (tile >> 2) * BM, bn = (tile & 3) * BN;
    int wn = w * 32;

    f32x4 acc[4][2] = {};
    int srow8 = l >> 3;
    int sk8b  = (((l & 7) ^ srow8) * 8);

    #pragma unroll
    for (int i = 0; i < 2; i++) {
        int c = w * 2 + i;
        load_lds16(A + (size_t)(bm + c * 8 + srow8) * K + sk8b, &At[0][c * 512]);
    }
    #pragma unroll
    for (int i = 0; i < 4; i++) {
        int c = w * 4 + i;
        load_lds16(Bt + (size_t)(bn + c * 8 + srow8) * K + sk8b, &Bts[0][c * 512]);
    }
    __syncthreads();

    for (int k0 = 0; k0 < K; k0 += BK) {
        int cur = (k0 >> 6) & 1;
        if (k0 + BK < K) {
            #pragma unroll
            for (int i = 0; i < 2; i++) {
                int c = w * 2 + i;
                load_lds16(A + (size_t)(bm + c * 8 + srow8) * K + k0 + BK + sk8b,
                           &At[cur ^ 1][c * 512]);
            }
            #pragma unroll
            for (int i = 0; i < 4; i++) {
                int c = w * 4 + i;
                load_lds16(Bt + (size_t)(bn + c * 8 + srow8) * K + k0 + BK + sk8b,
                           &Bts[cur ^ 1][c * 512]);
            }
        }
        #pragma unroll
        for (int kk = 0; kk < BK; kk += 32) {
            short8 af[4], bfr[2];
            int slot = (((kk >> 3) + (l >> 4)) ^ (l & 7)) * 8;
            #pragma unroll
            for (int i = 0; i < 4; i++)
                af[i] = *(const short8*)&At[cur][(i * 16 + (l & 15)) * BK + slot];
            #pragma unroll
            for (int j = 0; j < 2; j++)
                bfr[j] = *(const short8*)&Bts[cur][(wn + j * 16 + (l & 15)) * BK + slot];
            #pragma unroll
            for (int i = 0; i < 4; i++)
                #pragma unroll
                for (int j = 0; j < 2; j++)
                    acc[i][j] = __builtin_amdgcn_mfma_f32_16x16x32_bf16(
                                    af[i], bfr[j], acc[i][j], 0, 0, 0);
        }
        __syncthreads();
    }

    int col = l & 15, rq = (l >> 4) * 4;
    #pragma unroll
    for (int i = 0; i < 4; i++) {
        #pragma unroll
        for (int r = 0; r < 4; r++) {
            int gm = bm + i * 16 + rq + r;
            if (gm >= M) continue;
            float rs = rsqrtf((float)deg[gm] + 1.0f);
            #pragma unroll
            for (int j = 0; j < 2; j++) {
                int gn = bn + wn + j * 16 + col;
                C[(size_t)gm * Nc + gn] = __float2bfloat16(acc[i][j][r] * rs);
            }
        }
    }
}

// ---- gather (ELL) v2: XCD-affine chunking kept (confirmed L2-hot: r4 HBM 5.5%),
//      VALU-bound inner loop restructured (r4: VALUBusy 79.5%).
//      Lane-quarter q handles edge e+q; each lane loads dwordx4 (8 cols of its
//      quarter's row). Per 4 edges: 1 shfl + 1 addr + 1 load (vs 4/12/4 before).
//      Epilogue: shfl_xor(16,32) folds quarters; lanes 0-15 store uint4. ----
__global__ __launch_bounds__(256) void gather_ell(
        const int* __restrict__ cursor, const int* __restrict__ ell,
        const bf16* __restrict__ Hs, const float* __restrict__ bias,
        bf16* __restrict__ Out, int relu) {
    int t = threadIdx.x;
    int w = t >> 6, lane = t & 63;
    int chunk = blockIdx.x & 3;
    int wid = (blockIdx.x >> 2) * 4 + w;
    if (wid >= N_NODES) return;
    int q = lane >> 4;                        // edge-quarter 0..3
    int c0 = chunk * 128 + (lane & 15) * 8;   // this lane's 8-col group
    int cnt0 = cursor[wid];
    int cnt = min(cnt0, ELLW);
    int idx = ell[wid * ELLW + lane];         // lane i holds edge-index i

    float acc[8] = {};
    if (q == 0) {                             // self-loop counted once
        uint4 sv = *(const uint4*)(Hs + (size_t)wid * DIM + c0);
        const u32* p = (const u32*)&sv;
        #pragma unroll
        for (int j = 0; j < 4; j++) { acc[2*j] += blo(p[j]); acc[2*j+1] += bhi(p[j]); }
    }

    int e = 0;
    for (; e + 8 <= cnt; e += 8) {            // 2-deep: 2 loads in flight
        int s0 = __shfl(idx, e + q, 64);
        int s1 = __shfl(idx, e + 4 + q, 64);
        uint4 r0 = *(const uint4*)(Hs + (size_t)s0 * DIM + c0);
        uint4 r1 = *(const uint4*)(Hs + (size_t)s1 * DIM + c0);
        const u32* p0 = (const u32*)&r0;
        const u32* p1 = (const u32*)&r1;
        #pragma unroll
        for (int j = 0; j < 4; j++) {
            acc[2*j]   += blo(p0[j]) + blo(p1[j]);
            acc[2*j+1] += bhi(p0[j]) + bhi(p1[j]);
        }
    }
    for (; e + 4 <= cnt; e += 4) {
        int s = __shfl(idx, e + q, 64);
        uint4 rv = *(const uint4*)(Hs + (size_t)s * DIM + c0);
        const u32* p = (const u32*)&rv;
        #pragma unroll
        for (int j = 0; j < 4; j++) { acc[2*j] += blo(p[j]); acc[2*j+1] += bhi(p[j]); }
    }
    if (e < cnt) {                            // tail 1..3 edges
        int ee = e + q;
        int s = __shfl(idx, ee < cnt ? ee : 0, 64);   // clamped src always valid
        if (ee < cnt) {
            uint4 rv = *(const uint4*)(Hs + (size_t)s * DIM + c0);
            const u32* p = (const u32*)&rv;
            #pragma unroll
            for (int j = 0; j < 4; j++) { acc[2*j] += blo(p[j]); acc[2*j+1] += bhi(p[j]); }
        }
    }

    #pragma unroll
    for (int j = 0; j < 8; j++) {             // fold the 4 quarters
        acc[j] += __shfl_xor(acc[j], 16, 64);
        acc[j] += __shfl_xor(acc[j], 32, 64);
    }

    if (q == 0) {                             // lanes 0-15 write 256B
        float ds = rsqrtf((float)cnt0 + 1.0f);
        u16 o[8];
        #pragma unroll
        for (int j = 0; j < 8; j++) {
            float v = acc[j] * ds + bias[c0 + j];
            if (relu) v = fmaxf(v, 0.0f);
            o[j] = f2b(v);
        }
        *(uint4*)(Out + (size_t)wid * DIM + c0) = *(uint4*)o;
    }
}

// ---- fused classifier + bias + log-softmax: one wave per 16 rows, no LDS ----
__global__ __launch_bounds__(64) void cls_lsm_kernel(
        const bf16* __restrict__ A, const bf16* __restrict__ Wct,
        const float* __restrict__ bias, float* __restrict__ out, int M) {
    int l = threadIdx.x;
    int row0 = blockIdx.x * 16;
    int q = l >> 4, col15 = l & 15;

    f32x4 acc[4] = {};
    #pragma unroll 4
    for (int k0 = 0; k0 < DIM; k0 += 32) {
        short8 af = *(const short8*)&A[(size_t)(row0 + col15) * DIM + k0 + q * 8];
        #pragma unroll
        for (int j = 0; j < 4; j++) {
            short8 bfr = *(const short8*)&Wct[(size_t)(j * 16 + col15) * DIM + k0 + q * 8];
            acc[j] = __builtin_amdgcn_mfma_f32_16x16x32_bf16(af, bfr, acc[j], 0, 0, 0);
        }
    }

    float bcol[4];
    #pragma unroll
    for (int j = 0; j < 4; j++) bcol[j] = bias[j * 16 + col15];

    #pragma unroll
    for (int r = 0; r < 4; r++) {
        int row = row0 + q * 4 + r;
        float v[4];
        #pragma unroll
        for (int j = 0; j < 4; j++) v[j] = acc[j][r] + bcol[j];
        float m = fmaxf(fmaxf(v[0], v[1]), fmaxf(v[2], v[3]));
        #pragma unroll
        for (int o = 8; o > 0; o >>= 1) m = fmaxf(m, __shfl_xor(m, o, 64));
        float s = __expf(v[0] - m) + __expf(v[1] - m) + __expf(v[2] - m) + __expf(v[3] - m);
        #pragma unroll
        for (int o = 8; o > 0; o >>= 1) s += __shfl_xor(s, o, 64);
        float lse = m + __logf(s);
        if (row < M) {
            #pragma unroll
            for (int j = 0; j < 4; j++) {
                out[(size_t)row * NCLS + j * 16 + col15] = v[j];
                out[(size_t)M * NCLS + (size_t)row * NCLS + j * 16 + col15] = v[j] - lse;
            }
        }
    }
}

extern "C" void kernel_launch(void* const* d_in, const int* in_sizes, int n_in,
                              void* d_out, int out_size, void* d_ws, size_t ws_size,
                              hipStream_t stream) {
    const void* x  = d_in[0];
    const int*  ei = (const int*)d_in[1];
    const void* W1 = d_in[2];
    const void* b1 = d_in[3];
    const void* W2 = d_in[4];
    const void* b2 = d_in[5];
    const void* Wc = d_in[6];
    const void* bc = d_in[7];
    float* out = (float*)d_out;
    int E = in_sizes[1] / 2;

    // workspace layout (~38 MB; A-operand buffers padded to 10240 rows)
    char* ws = (char*)d_ws;
    float* bF1    = (float*)ws;                      // 2 KB
    float* bF2    = (float*)(ws + 4096);             // 2 KB
    float* bFc    = (float*)(ws + 8192);             // 256 B
    int*   cursor = (int*)(ws + 65536);              // 40 KB
    int*   ell    = (int*)(ws + 131072);             // 2.56 MB
    bf16*  xb     = (bf16*) (ws + 4194304);          // 10240 rows x 512 bf16
    bf16*  Wt1    = (bf16*) (ws + 14680064);         // 512 KB
    bf16*  Wt2    = (bf16*) (ws + 15204352);         // 512 KB
    bf16*  Wct    = (bf16*) (ws + 15728640);         // 64 KB
    bf16*  B0     = (bf16*) (ws + 16777216);         // 10240 rows
    bf16*  B1     = (bf16*) (ws + 27262976);         // 10240 rows

    int gConv = 3045 + (E + 255) / 256;
    const int GEMM_GRID = 628;                       // 157 row-panels x 4 col-tiles

    // ---- preamble ----
    hipMemsetAsync(cursor, 0, N_NODES * sizeof(int), stream);
    convert_all<<<gConv, 256, 0, stream>>>(x, W1, W2, Wc, b1, b2, bc, ei,
                                           cursor, ell, xb, Wt1, Wt2, Wct,
                                           bF1, bF2, bFc, E);

    // ---- layer 1 ----
    gemm_mfma<<<GEMM_GRID, 256, 0, stream>>>(xb, Wt1, B0, N_NODES, DIM, DIM, cursor);
    gather_ell<<<N_NODES, 256, 0, stream>>>(cursor, ell, B0, bF1, B1, 1);

    // ---- layer 2 ----
    gemm_mfma<<<GEMM_GRID, 256, 0, stream>>>(B1, Wt2, B0, N_NODES, DIM, DIM, cursor);
    gather_ell<<<N_NODES, 256, 0, stream>>>(cursor, ell, B0, bF2, B1, 0);

    // ---- fused classifier + log-softmax ----
    cls_lsm_kernel<<<(N_NODES + 15) / 16, 64, 0, stream>>>(B1, Wct, bFc, out, N_NODES);
}